// Round 7
// baseline (245.682 us; speedup 1.0000x reference)
//
#include <hip/hip_runtime.h>
#include <hip/hip_bf16.h>

#define N_ATOMS 20000
#define N_BONDS 200000
#define MAX_DEG 12
#define IN_DIM 256
#define BOND_DIM 128
#define OUT_DIM 512
#define N_HEADS 8
#define HEAD_DIM 64

typedef __attribute__((ext_vector_type(8))) short short8v;
typedef __attribute__((ext_vector_type(4))) float f32x4;

static __device__ __forceinline__ float bf2f(unsigned int u) {
    union { unsigned int i; float f; } c;
    c.i = (u & 0xffffu) << 16;
    return c.f;
}
static __device__ __forceinline__ unsigned short f2bf(float f) {
    union { float f; unsigned int i; } c;
    c.f = f;
    unsigned int x = c.i;
    x += 0x7fffu + ((x >> 16) & 1u);   // round-to-nearest-even
    return (unsigned short)(x >> 16);
}

// ---------------------------------------------------------------------------
// Wt[n][k] = bf16(W[k][n])  (N fixed 512)
// ---------------------------------------------------------------------------
__global__ void wt_kernel(const float* __restrict__ W, unsigned short* __restrict__ Wt,
                          int K) {
    int id = blockIdx.x * 256 + threadIdx.x;
    if (id >= K * 512) return;
    int n = id / K, k = id % K;
    Wt[id] = f2bf(W[(size_t)k * 512 + n]);
}

// ---------------------------------------------------------------------------
// BOND GEMM v3: H[m][512] = edge[m][128] @ WtB^T + bias.
// Block = one 128-col group x FOUR 64-row tiles. B (32 KB) staged ONCE via
// global_load_lds (linear dest + inverse-swizzled source, rule #21), one
// barrier, then a barrier-free loop: A prefetched to registers (wave-private,
// fragment-shaped), double-buffered across iterations (fully unrolled ->
// static indexing). Stores/loads of adjacent tiles overlap MFMAs freely.
// Grid 3128 = 8 * 391: bijective XCD chunking, 4 col-siblings share A in L2.
// ---------------------------------------------------------------------------
__global__ __launch_bounds__(256, 4) void bond_gemm(
    const float* __restrict__ A, const unsigned short* __restrict__ Wt,
    const float* __restrict__ bias, unsigned short* __restrict__ H) {
    __shared__ unsigned short Bls[128 * 128];     // 32 KB
    const int t = threadIdx.x;
    const int w = t >> 6, l = t & 63;

    // ---- bijective XCD-chunked swizzle: NW = 3128 = 8*391 ----
    const int wgid = (blockIdx.x & 7) * 391 + (blockIdx.x >> 3);
    const int bn = wgid & 3;                      // 4 col tiles of 128
    const int rblk = wgid >> 2;                   // 0..781, 4 row-tiles each

    const int m16 = l & 15, g = l >> 4;
    const int arow = (w << 4) + m16;

    // ---- prefetch A for tile 0 (in flight during B staging) ----
    f32x4 a0[2][4], a1[2][4];
    {
        const float* Ar = A + (size_t)(rblk * 4 * 64 + arow) * 128 + (g << 3);
        #pragma unroll
        for (int ks = 0; ks < 4; ++ks) {
            a0[0][ks] = *(const f32x4*)(Ar + (ks << 5));
            a1[0][ks] = *(const f32x4*)(Ar + (ks << 5) + 4);
        }
    }

    // ---- stage B once: WtB rows bn*128..+128, 2048 slots of 16B; 16/row.
    // LDS image: slot(n,kc) = n*16 + (kc ^ (n&7)); linear dest => source
    // chunk for slot s: n = s>>4, kc = (s&15)^(n&7). Dest is wave-uniform
    // base + lane*16 (HW rule), source is per-lane.
    {
        const char* Wb = (const char*)(Wt + (size_t)bn * 128 * 128);
        #pragma unroll
        for (int i = 0; i < 8; ++i) {
            int s = (w << 9) + (i << 6) + l;              // 0..2047
            int n = s >> 4;
            int kc = (s & 15) ^ (n & 7);
            const char* src = Wb + n * 256 + kc * 16;
            __builtin_amdgcn_global_load_lds(
                (const __attribute__((address_space(1))) void*)src,
                (__attribute__((address_space(3))) void*)((char*)Bls + (((w << 9) + (i << 6)) << 4)),
                16, 0, 0);
        }
    }
    __syncthreads();

    // ---- barrier-free loop over 4 row-tiles, A double-buffered ----
    #pragma unroll
    for (int it = 0; it < 4; ++it) {
        const int cur = it & 1, nxt = cur ^ 1;
        const int tt = rblk * 4 + it;

        if (it < 3) {                              // prefetch next tile's A
            const int tn = tt + 1;
            if (tn < 3125) {
                const float* Ar = A + (size_t)(tn * 64 + arow) * 128 + (g << 3);
                #pragma unroll
                for (int ks = 0; ks < 4; ++ks) {
                    a0[nxt][ks] = *(const f32x4*)(Ar + (ks << 5));
                    a1[nxt][ks] = *(const f32x4*)(Ar + (ks << 5) + 4);
                }
            }
        }

        if (tt < 3125) {
            short8v afr[4];
            #pragma unroll
            for (int ks = 0; ks < 4; ++ks) {
                union { unsigned short us[8]; short8v v; } pk;
                pk.us[0] = f2bf(a0[cur][ks][0]); pk.us[1] = f2bf(a0[cur][ks][1]);
                pk.us[2] = f2bf(a0[cur][ks][2]); pk.us[3] = f2bf(a0[cur][ks][3]);
                pk.us[4] = f2bf(a1[cur][ks][0]); pk.us[5] = f2bf(a1[cur][ks][1]);
                pk.us[6] = f2bf(a1[cur][ks][2]); pk.us[7] = f2bf(a1[cur][ks][3]);
                afr[ks] = pk.v;
            }

            f32x4 acc[8] = {};
            #pragma unroll
            for (int ks = 0; ks < 4; ++ks) {
                #pragma unroll
                for (int nt = 0; nt < 8; ++nt) {
                    int n = (nt << 4) + m16;
                    const short8v b = *(const short8v*)((const char*)Bls +
                        ((n * 256 + (ks << 6) + (g << 4)) ^ ((n & 7) << 4)));
                    acc[nt] = __builtin_amdgcn_mfma_f32_16x16x32_bf16(afr[ks], b, acc[nt], 0, 0, 0);
                }
            }

            // ---- epilogue (verified layout): row = (l>>4)*4 + r, col = l&15 ----
            const int rbase = (tt << 6) + (w << 4) + (g << 2);
            #pragma unroll
            for (int nt = 0; nt < 8; ++nt) {
                int col = (bn << 7) + (nt << 4) + m16;
                float bv = bias[col];
                #pragma unroll
                for (int r = 0; r < 4; ++r)
                    H[(size_t)(rbase + r) * 512 + col] = f2bf(acc[nt][r] + bv);
            }
        }
    }
}

// ---------------------------------------------------------------------------
// ATOM GEMM (round-4, proven): tiles 64x64x64, 4 waves, XCD-chunked swizzle.
// ---------------------------------------------------------------------------
__global__ __launch_bounds__(256) void gemm_kernel(
    const float* __restrict__ A, const unsigned short* __restrict__ Wt,
    const float* __restrict__ bias, unsigned short* __restrict__ H,
    int M, int K, int nbm) {
    __shared__ unsigned short Als[64 * 64];
    __shared__ unsigned short Bls[64 * 64];
    const int t = threadIdx.x;
    const int q = nbm;
    const int wgid = (blockIdx.x & 7) * q + (blockIdx.x >> 3);
    const int bn = wgid & 7;
    const int bm = wgid >> 3;
    const int w = t >> 6;
    const int l = t & 63;

    f32x4 acc[4] = {};

    const int nk = K >> 6;
    for (int kk = 0; kk < nk; ++kk) {
        #pragma unroll
        for (int i = 0; i < 2; ++i) {
            int c = t + i * 256;
            int row = c >> 3;
            int k8 = (c & 7) << 3;
            int grow = (bm << 6) + row;
            float f[8];
            if (grow < M) {
                const float* src = A + (size_t)grow * K + (kk << 6) + k8;
                float4 v0 = *(const float4*)src;
                float4 v1 = *(const float4*)(src + 4);
                f[0] = v0.x; f[1] = v0.y; f[2] = v0.z; f[3] = v0.w;
                f[4] = v1.x; f[5] = v1.y; f[6] = v1.z; f[7] = v1.w;
            } else {
                #pragma unroll
                for (int j = 0; j < 8; ++j) f[j] = 0.f;
            }
            union { unsigned short us[8]; uint4 v; } pk;
            #pragma unroll
            for (int j = 0; j < 8; ++j) pk.us[j] = f2bf(f[j]);
            int byte = ((row << 7) + (k8 << 1)) ^ ((row & 7) << 4);
            *(uint4*)((char*)Als + byte) = pk.v;
        }
        #pragma unroll
        for (int i = 0; i < 2; ++i) {
            int c = t + i * 256;
            int row = c >> 3;
            int k8 = (c & 7) << 3;
            int gn = (bn << 6) + row;
            uint4 v = *(const uint4*)(Wt + (size_t)gn * K + (kk << 6) + k8);
            int byte = ((row << 7) + (k8 << 1)) ^ ((row & 7) << 4);
            *(uint4*)((char*)Bls + byte) = v;
        }
        __syncthreads();

        const int m = l & 15;
        const int kg = (l >> 4) << 3;
        #pragma unroll
        for (int ks = 0; ks < 2; ++ks) {
            int kcol = (ks << 5) + kg;
            int arow = (w << 4) + m;
            short8v a = *(short8v*)((char*)Als +
                (((arow << 7) + (kcol << 1)) ^ ((arow & 7) << 4)));
            #pragma unroll
            for (int nt = 0; nt < 4; ++nt) {
                int nrow = (nt << 4) + m;
                short8v b = *(short8v*)((char*)Bls +
                    (((nrow << 7) + (kcol << 1)) ^ ((nrow & 7) << 4)));
                acc[nt] = __builtin_amdgcn_mfma_f32_16x16x32_bf16(a, b, acc[nt], 0, 0, 0);
            }
        }
        __syncthreads();
    }

    const int m = l & 15;
    const int rbase = (bm << 6) + (w << 4) + ((l >> 4) << 2);
    #pragma unroll
    for (int nt = 0; nt < 4; ++nt) {
        int col = (bn << 6) + (nt << 4) + m;
        float bv = bias[col];
        #pragma unroll
        for (int r = 0; r < 4; ++r) {
            int grow = rbase + r;
            if (grow < M) H[(size_t)grow * 512 + col] = f2bf(acc[nt][r] + bv);
        }
    }
}

// ---------------------------------------------------------------------------
// Fused gather + attention + softmax(deg) + weighted sum.
// ---------------------------------------------------------------------------
__global__ __launch_bounds__(256) void attn_kernel(
    const unsigned short* __restrict__ hA,
    const unsigned short* __restrict__ hB,
    const float* __restrict__ att_src,
    const float* __restrict__ att_dst,
    const float* __restrict__ att_edge,
    const int* __restrict__ a2a,
    const int* __restrict__ a2b,
    float* __restrict__ out) {
    const int w = threadIdx.x >> 6;
    const int l = threadIdx.x & 63;
    const int n = blockIdx.x * 4 + w;
    if (n >= N_ATOMS) return;

    float as[8], ad[8], ae[8];
    {
        float4 v0 = *(const float4*)(att_src + l * 8);
        float4 v1 = *(const float4*)(att_src + l * 8 + 4);
        as[0]=v0.x; as[1]=v0.y; as[2]=v0.z; as[3]=v0.w;
        as[4]=v1.x; as[5]=v1.y; as[6]=v1.z; as[7]=v1.w;
        v0 = *(const float4*)(att_dst + l * 8);
        v1 = *(const float4*)(att_dst + l * 8 + 4);
        ad[0]=v0.x; ad[1]=v0.y; ad[2]=v0.z; ad[3]=v0.w;
        ad[4]=v1.x; ad[5]=v1.y; ad[6]=v1.z; ad[7]=v1.w;
        v0 = *(const float4*)(att_edge + l * 8);
        v1 = *(const float4*)(att_edge + l * 8 + 4);
        ae[0]=v0.x; ae[1]=v0.y; ae[2]=v0.z; ae[3]=v0.w;
        ae[4]=v1.x; ae[5]=v1.y; ae[6]=v1.z; ae[7]=v1.w;
    }

    float s_src;
    {
        uint4 u = *(const uint4*)(hA + (size_t)n * 512 + l * 8);
        float p = bf2f(u.x) * as[0] + bf2f(u.x >> 16) * as[1]
                + bf2f(u.y) * as[2] + bf2f(u.y >> 16) * as[3]
                + bf2f(u.z) * as[4] + bf2f(u.z >> 16) * as[5]
                + bf2f(u.w) * as[6] + bf2f(u.w >> 16) * as[7];
        p += __shfl_xor(p, 1);
        p += __shfl_xor(p, 2);
        p += __shfl_xor(p, 4);
        s_src = p;
    }

    float mrun = -1e30f, lsum = 0.f;
    float acc[8];
    #pragma unroll
    for (int j = 0; j < 8; ++j) acc[j] = 0.f;

    const int* pa = a2a + n * MAX_DEG;
    const int* pb = a2b + n * MAX_DEG;

    #pragma unroll 4
    for (int d = 0; d < MAX_DEG; ++d) {
        const int ia = pa[d];
        const int ib = pb[d];
        const bool valid = (ia != 0);
        uint4 ua = *(const uint4*)(hA + (size_t)ia * 512 + l * 8);
        uint4 ub = *(const uint4*)(hB + (size_t)ib * 512 + l * 8);
        float fa[8], fb[8];
        fa[0]=bf2f(ua.x); fa[1]=bf2f(ua.x>>16); fa[2]=bf2f(ua.y); fa[3]=bf2f(ua.y>>16);
        fa[4]=bf2f(ua.z); fa[5]=bf2f(ua.z>>16); fa[6]=bf2f(ua.w); fa[7]=bf2f(ua.w>>16);
        fb[0]=bf2f(ub.x); fb[1]=bf2f(ub.x>>16); fb[2]=bf2f(ub.y); fb[3]=bf2f(ub.y>>16);
        fb[4]=bf2f(ub.z); fb[5]=bf2f(ub.z>>16); fb[6]=bf2f(ub.w); fb[7]=bf2f(ub.w>>16);

        float p = 0.f;
        #pragma unroll
        for (int j = 0; j < 8; ++j) p += fa[j] * ad[j] + fb[j] * ae[j];
        p += __shfl_xor(p, 1);
        p += __shfl_xor(p, 2);
        p += __shfl_xor(p, 4);

        float sc = s_src + p;
        sc = sc > 0.f ? sc : 0.2f * sc;         // leaky_relu(0.2)

        float mn = valid ? fmaxf(mrun, sc) : mrun;
        float scale = __expf(mrun - mn);        // ==1 when masked
        float pw = valid ? __expf(sc - mn) : 0.f;
        lsum = lsum * scale + pw;
        #pragma unroll
        for (int j = 0; j < 8; ++j)
            acc[j] = acc[j] * scale + pw * (fa[j] + fb[j]);
        mrun = mn;
    }

    float inv = lsum > 0.f ? 1.f / lsum : 0.f;
    float4 o0, o1;
    o0.x = acc[0]*inv; o0.y = acc[1]*inv; o0.z = acc[2]*inv; o0.w = acc[3]*inv;
    o1.x = acc[4]*inv; o1.y = acc[5]*inv; o1.z = acc[6]*inv; o1.w = acc[7]*inv;
    float* dst = out + (size_t)n * 512 + l * 8;
    *(float4*)dst = o0;
    *(float4*)(dst + 4) = o1;
}

// ---------------------------------------------------------------------------
extern "C" void kernel_launch(void* const* d_in, const int* in_sizes, int n_in,
                              void* d_out, int out_size, void* d_ws, size_t ws_size,
                              hipStream_t stream) {
    const float* x        = (const float*)d_in[0];
    const float* edge     = (const float*)d_in[1];
    const float* W_atom   = (const float*)d_in[2];
    const float* b_atom   = (const float*)d_in[3];
    const float* W_bond   = (const float*)d_in[4];
    const float* b_bond   = (const float*)d_in[5];
    const float* att_src  = (const float*)d_in[6];
    const float* att_dst  = (const float*)d_in[7];
    const float* att_edge = (const float*)d_in[8];
    const int*   a2a      = (const int*)d_in[9];
    const int*   a2b      = (const int*)d_in[10];
    float* out = (float*)d_out;

    char* ws = (char*)d_ws;
    unsigned short* hA  = (unsigned short*)ws;                               // 20,480,000 B
    unsigned short* hB  = (unsigned short*)(ws + 20480000);                  // 204,800,000 B
    unsigned short* WtA = (unsigned short*)(ws + 20480000 + 204800000);      // 262,144 B
    unsigned short* WtB = WtA + 512 * 256;                                   // 131,072 B

    wt_kernel<<<(512 * 256 + 255) / 256, 256, 0, stream>>>(W_atom, WtA, 256);
    wt_kernel<<<(512 * 128 + 255) / 256, 256, 0, stream>>>(W_bond, WtB, 128);

    // atoms: 313 row-tiles x 8 col-tiles (round-4 kernel)
    gemm_kernel<<<313 * 8, 256, 0, stream>>>(x, WtA, b_atom, hA, N_ATOMS, 256, 313);
    // bonds: 4 col-groups x 782 row-blocks (4 row-tiles each) = 3128 blocks
    bond_gemm<<<3128, 256, 0, stream>>>(edge, WtB, b_bond, hB);

    attn_kernel<<<(N_ATOMS + 3) / 4, 256, 0, stream>>>(
        hA, hB, att_src, att_dst, att_edge, a2a, a2b, out);
}

// Round 8
// 208.280 us; speedup vs baseline: 1.1796x; 1.1796x over previous
//
#include <hip/hip_runtime.h>
#include <hip/hip_bf16.h>

#define N_ATOMS 20000
#define N_BONDS 200000
#define MAX_DEG 12
#define IN_DIM 256
#define BOND_DIM 128
#define OUT_DIM 512
#define N_HEADS 8
#define HEAD_DIM 64

typedef __attribute__((ext_vector_type(8))) short short8v;
typedef __attribute__((ext_vector_type(4))) float f32x4;

static __device__ __forceinline__ float bf2f(unsigned int u) {
    union { unsigned int i; float f; } c;
    c.i = (u & 0xffffu) << 16;
    return c.f;
}
static __device__ __forceinline__ unsigned short f2bf(float f) {
    union { float f; unsigned int i; } c;
    c.f = f;
    unsigned int x = c.i;
    x += 0x7fffu + ((x >> 16) & 1u);   // round-to-nearest-even
    return (unsigned short)(x >> 16);
}

// ---------------------------------------------------------------------------
// Wt[n][k] = bf16(W[k][n])  (N fixed 512)
// ---------------------------------------------------------------------------
__global__ void wt_kernel(const float* __restrict__ W, unsigned short* __restrict__ Wt,
                          int K) {
    int id = blockIdx.x * 256 + threadIdx.x;
    if (id >= K * 512) return;
    int n = id / K, k = id % K;
    Wt[id] = f2bf(W[(size_t)k * 512 + n]);
}

// ---------------------------------------------------------------------------
// u_edge[h][c] = sum_k W_bond[c][h*64+k] * att_edge[h][k];  c_edge[h] = b_bond.att_edge
// ---------------------------------------------------------------------------
__global__ void uedge_kernel(const float* __restrict__ Wb, const float* __restrict__ att_edge,
                             const float* __restrict__ b_bond,
                             float* __restrict__ u_edge, float* __restrict__ c_edge) {
    int tid = blockIdx.x * 256 + threadIdx.x;
    if (tid >= 1024) return;
    int h = tid >> 7, c = tid & 127;
    const float* wrow = Wb + (size_t)c * 512 + h * 64;
    const float* ae = att_edge + h * 64;
    float s = 0.f;
    #pragma unroll 8
    for (int k = 0; k < 64; ++k) s += wrow[k] * ae[k];
    u_edge[h * 128 + c] = s;
    if (c == 0) {
        float cs = 0.f;
        const float* bb = b_bond + h * 64;
        for (int k = 0; k < 64; ++k) cs += bb[k] * ae[k];
        c_edge[h] = cs;
    }
}

// ---------------------------------------------------------------------------
// Per-atom score tables from hA: s_src_all[n][h], s_dst_all[n][h].
// ---------------------------------------------------------------------------
__global__ __launch_bounds__(256) void sdots_kernel(
    const unsigned short* __restrict__ hA,
    const float* __restrict__ att_src, const float* __restrict__ att_dst,
    float* __restrict__ s_src_all, float* __restrict__ s_dst_all) {
    const int w = threadIdx.x >> 6, l = threadIdx.x & 63;
    const int n = blockIdx.x * 4 + w;
    if (n >= N_ATOMS) return;
    float4 s0 = *(const float4*)(att_src + l * 8);
    float4 s1 = *(const float4*)(att_src + l * 8 + 4);
    float4 d0 = *(const float4*)(att_dst + l * 8);
    float4 d1 = *(const float4*)(att_dst + l * 8 + 4);
    uint4 u = *(const uint4*)(hA + (size_t)n * 512 + l * 8);
    float fa[8];
    fa[0]=bf2f(u.x); fa[1]=bf2f(u.x>>16); fa[2]=bf2f(u.y); fa[3]=bf2f(u.y>>16);
    fa[4]=bf2f(u.z); fa[5]=bf2f(u.z>>16); fa[6]=bf2f(u.w); fa[7]=bf2f(u.w>>16);
    float ps = fa[0]*s0.x + fa[1]*s0.y + fa[2]*s0.z + fa[3]*s0.w
             + fa[4]*s1.x + fa[5]*s1.y + fa[6]*s1.z + fa[7]*s1.w;
    float pd = fa[0]*d0.x + fa[1]*d0.y + fa[2]*d0.z + fa[3]*d0.w
             + fa[4]*d1.x + fa[5]*d1.y + fa[6]*d1.z + fa[7]*d1.w;
    ps += __shfl_xor(ps, 1); ps += __shfl_xor(ps, 2); ps += __shfl_xor(ps, 4);
    pd += __shfl_xor(pd, 1); pd += __shfl_xor(pd, 2); pd += __shfl_xor(pd, 4);
    if ((l & 7) == 0) {
        s_src_all[n * 8 + (l >> 3)] = ps;
        s_dst_all[n * 8 + (l >> 3)] = pd;
    }
}

// ---------------------------------------------------------------------------
// score_edge[b][h] = edge[b] . u_edge[h] + c_edge[h].  32 bonds/block.
// ---------------------------------------------------------------------------
__global__ __launch_bounds__(256) void escore_kernel(
    const float* __restrict__ edge, const float* __restrict__ u_edge,
    const float* __restrict__ c_edge, float* __restrict__ score_edge) {
    __shared__ float eL[32 * 132];       // padded rows (bank-spread)
    __shared__ float uL[8 * 132];
    __shared__ float cL[8];
    const int t = threadIdx.x;
    const size_t b0 = (size_t)blockIdx.x * 32;
    #pragma unroll
    for (int i = 0; i < 4; ++i) {
        int idx = i * 256 + t;           // f32x4 chunk 0..1023
        int row = idx >> 5, c4 = idx & 31;
        *(float4*)(eL + row * 132 + c4 * 4) = *(const float4*)(edge + b0 * 128 + idx * 4);
    }
    {
        int h = t >> 5, c4 = t & 31;
        *(float4*)(uL + h * 132 + c4 * 4) = *(const float4*)(u_edge + h * 128 + c4 * 4);
    }
    if (t < 8) cL[t] = c_edge[t];
    __syncthreads();
    const int b2 = t >> 3, h = t & 7;
    float s = 0.f;
    #pragma unroll
    for (int c4 = 0; c4 < 32; ++c4) {
        float4 e = *(const float4*)(eL + b2 * 132 + c4 * 4);
        float4 u = *(const float4*)(uL + h * 132 + c4 * 4);
        s += e.x*u.x + e.y*u.y + e.z*u.z + e.w*u.w;
    }
    score_edge[(b0 + b2) * 8 + h] = s + cL[h];
}

// ---------------------------------------------------------------------------
// ATOM GEMM (round-4, proven): tiles 64x64x64, 4 waves, XCD-chunked swizzle.
// ---------------------------------------------------------------------------
__global__ __launch_bounds__(256) void gemm_kernel(
    const float* __restrict__ A, const unsigned short* __restrict__ Wt,
    const float* __restrict__ bias, unsigned short* __restrict__ H,
    int M, int K, int nbm) {
    __shared__ unsigned short Als[64 * 64];
    __shared__ unsigned short Bls[64 * 64];
    const int t = threadIdx.x;
    const int wgid = (blockIdx.x & 7) * nbm + (blockIdx.x >> 3);
    const int bn = wgid & 7;
    const int bm = wgid >> 3;
    const int w = t >> 6;
    const int l = t & 63;

    f32x4 acc[4] = {};

    const int nk = K >> 6;
    for (int kk = 0; kk < nk; ++kk) {
        #pragma unroll
        for (int i = 0; i < 2; ++i) {
            int c = t + i * 256;
            int row = c >> 3;
            int k8 = (c & 7) << 3;
            int grow = (bm << 6) + row;
            float f[8];
            if (grow < M) {
                const float* src = A + (size_t)grow * K + (kk << 6) + k8;
                float4 v0 = *(const float4*)src;
                float4 v1 = *(const float4*)(src + 4);
                f[0] = v0.x; f[1] = v0.y; f[2] = v0.z; f[3] = v0.w;
                f[4] = v1.x; f[5] = v1.y; f[6] = v1.z; f[7] = v1.w;
            } else {
                #pragma unroll
                for (int j = 0; j < 8; ++j) f[j] = 0.f;
            }
            union { unsigned short us[8]; uint4 v; } pk;
            #pragma unroll
            for (int j = 0; j < 8; ++j) pk.us[j] = f2bf(f[j]);
            int byte = ((row << 7) + (k8 << 1)) ^ ((row & 7) << 4);
            *(uint4*)((char*)Als + byte) = pk.v;
        }
        #pragma unroll
        for (int i = 0; i < 2; ++i) {
            int c = t + i * 256;
            int row = c >> 3;
            int k8 = (c & 7) << 3;
            int gn = (bn << 6) + row;
            uint4 v = *(const uint4*)(Wt + (size_t)gn * K + (kk << 6) + k8);
            int byte = ((row << 7) + (k8 << 1)) ^ ((row & 7) << 4);
            *(uint4*)((char*)Bls + byte) = v;
        }
        __syncthreads();

        const int m = l & 15;
        const int kg = (l >> 4) << 3;
        #pragma unroll
        for (int ks = 0; ks < 2; ++ks) {
            int kcol = (ks << 5) + kg;
            int arow = (w << 4) + m;
            short8v a = *(short8v*)((char*)Als +
                (((arow << 7) + (kcol << 1)) ^ ((arow & 7) << 4)));
            #pragma unroll
            for (int nt = 0; nt < 4; ++nt) {
                int nrow = (nt << 4) + m;
                short8v b = *(short8v*)((char*)Bls +
                    (((nrow << 7) + (kcol << 1)) ^ ((nrow & 7) << 4)));
                acc[nt] = __builtin_amdgcn_mfma_f32_16x16x32_bf16(a, b, acc[nt], 0, 0, 0);
            }
        }
        __syncthreads();
    }

    const int m = l & 15;
    const int rbase = (bm << 6) + (w << 4) + ((l >> 4) << 2);
    #pragma unroll
    for (int nt = 0; nt < 4; ++nt) {
        int col = (bn << 6) + (nt << 4) + m;
        float bv = bias[col];
        #pragma unroll
        for (int r = 0; r < 4; ++r) {
            int grow = rbase + r;
            if (grow < M) H[(size_t)grow * 512 + col] = f2bf(acc[nt][r] + bv);
        }
    }
}

// ---------------------------------------------------------------------------
// Fused attention: gathers hA rows + precomputed scores + edge rows.
// Each lane runs the 8-head online softmax redundantly (no shuffles);
// accumulates atom-value part (own 8 channels) and z[h] = sum alpha*edge
// (own 2 edge channels, all heads). Writes out (atom part, f32) and
// Z[n][h][128] bf16 (normalized weighted edge sum) for the projection pass.
// ---------------------------------------------------------------------------
__global__ __launch_bounds__(256) void attn_kernel(
    const unsigned short* __restrict__ hA,
    const float* __restrict__ edge,
    const float* __restrict__ s_src_all,
    const float* __restrict__ s_dst_all,
    const float* __restrict__ score_edge,
    const int* __restrict__ a2a,
    const int* __restrict__ a2b,
    float* __restrict__ out,
    unsigned short* __restrict__ Z) {
    const int w = threadIdx.x >> 6;
    const int l = threadIdx.x & 63;
    const int n = blockIdx.x * 4 + w;
    if (n >= N_ATOMS) return;
    const int hl = l >> 3;

    float ss[8];
    {
        float4 v0 = *(const float4*)(s_src_all + n * 8);
        float4 v1 = *(const float4*)(s_src_all + n * 8 + 4);
        ss[0]=v0.x; ss[1]=v0.y; ss[2]=v0.z; ss[3]=v0.w;
        ss[4]=v1.x; ss[5]=v1.y; ss[6]=v1.z; ss[7]=v1.w;
    }

    float mrun[8], lsum[8], acc[8], zx[8], zy[8];
    #pragma unroll
    for (int h = 0; h < 8; ++h) {
        mrun[h] = -1e30f; lsum[h] = 0.f; zx[h] = 0.f; zy[h] = 0.f;
    }
    #pragma unroll
    for (int j = 0; j < 8; ++j) acc[j] = 0.f;

    const int* pa = a2a + n * MAX_DEG;
    const int* pb = a2b + n * MAX_DEG;

    for (int d = 0; d < MAX_DEG; ++d) {
        const int ia = pa[d];
        const int ib = pb[d];
        const bool valid = (ia != 0);

        float4 sd0 = *(const float4*)(s_dst_all + ia * 8);
        float4 sd1 = *(const float4*)(s_dst_all + ia * 8 + 4);
        float4 se0 = *(const float4*)(score_edge + ib * 8);
        float4 se1 = *(const float4*)(score_edge + ib * 8 + 4);
        uint4 ua = *(const uint4*)(hA + (size_t)ia * 512 + l * 8);
        float2 ef = *(const float2*)(edge + (size_t)ib * 128 + l * 2);

        float sd[8], se[8];
        sd[0]=sd0.x; sd[1]=sd0.y; sd[2]=sd0.z; sd[3]=sd0.w;
        sd[4]=sd1.x; sd[5]=sd1.y; sd[6]=sd1.z; sd[7]=sd1.w;
        se[0]=se0.x; se[1]=se0.y; se[2]=se0.z; se[3]=se0.w;
        se[4]=se1.x; se[5]=se1.y; se[6]=se1.z; se[7]=se1.w;

        float pw[8], scale[8];
        #pragma unroll
        for (int h = 0; h < 8; ++h) {
            float sc = ss[h] + sd[h] + se[h];
            sc = sc > 0.f ? sc : 0.2f * sc;              // leaky_relu(0.2)
            float mn = valid ? fmaxf(mrun[h], sc) : mrun[h];
            scale[h] = __expf(mrun[h] - mn);
            pw[h] = valid ? __expf(sc - mn) : 0.f;
            lsum[h] = lsum[h] * scale[h] + pw[h];
            mrun[h] = mn;
        }

        float fa[8];
        fa[0]=bf2f(ua.x); fa[1]=bf2f(ua.x>>16); fa[2]=bf2f(ua.y); fa[3]=bf2f(ua.y>>16);
        fa[4]=bf2f(ua.z); fa[5]=bf2f(ua.z>>16); fa[6]=bf2f(ua.w); fa[7]=bf2f(ua.w>>16);

        const float sl = scale[hl], pl = pw[hl];
        #pragma unroll
        for (int j = 0; j < 8; ++j) acc[j] = acc[j] * sl + pl * fa[j];
        #pragma unroll
        for (int h = 0; h < 8; ++h) {
            zx[h] = zx[h] * scale[h] + pw[h] * ef.x;
            zy[h] = zy[h] * scale[h] + pw[h] * ef.y;
        }
    }

    float inv[8];
    #pragma unroll
    for (int h = 0; h < 8; ++h) inv[h] = lsum[h] > 0.f ? 1.f / lsum[h] : 0.f;

    const float il = inv[hl];
    float4 o0, o1;
    o0.x = acc[0]*il; o0.y = acc[1]*il; o0.z = acc[2]*il; o0.w = acc[3]*il;
    o1.x = acc[4]*il; o1.y = acc[5]*il; o1.z = acc[6]*il; o1.w = acc[7]*il;
    float* dst = out + (size_t)n * 512 + l * 8;
    *(float4*)dst = o0;
    *(float4*)(dst + 4) = o1;

    // Z[n][h][128] bf16, lane owns channels 2l, 2l+1
    #pragma unroll
    for (int h = 0; h < 8; ++h) {
        unsigned int pk = (unsigned int)f2bf(zx[h] * inv[h])
                        | ((unsigned int)f2bf(zy[h] * inv[h]) << 16);
        *(unsigned int*)(Z + (size_t)n * 1024 + h * 128 + l * 2) = pk;
    }
}

// ---------------------------------------------------------------------------
// Projection pass: out[n][h*64+j] += (Z[n][h] @ WtB_head) + b_bond.
// Single-shot 64x64 K=128 MFMA tile per block (bond-v2 structure):
// B (head slice of WtB, 16 KB) via global_load_lds, A (Z rows) to registers.
// ---------------------------------------------------------------------------
__global__ __launch_bounds__(256, 4) void proj_kernel(
    const unsigned short* __restrict__ Z, const unsigned short* __restrict__ WtB,
    const float* __restrict__ b_bond, float* __restrict__ out) {
    __shared__ unsigned short Bls[64 * 128];      // 16 KB
    const int t = threadIdx.x;
    const int w = t >> 6, l = t & 63;
    const int h = blockIdx.x & 7;                 // head
    const int mt = blockIdx.x >> 3;               // 0..312

    const int m16 = l & 15, g = l >> 4;
    const int arow = mt * 64 + (w << 4) + m16;    // atom row (may exceed 19999)

    // A: fragment-shaped Z loads (bf16 direct)
    const unsigned short* Zr = Z + (size_t)arow * 1024 + h * 128 + (g << 3);
    uint4 af[4];
    #pragma unroll
    for (int ks = 0; ks < 4; ++ks)
        af[ks] = *(const uint4*)(Zr + (ks << 5));

    // stage B: rows j=0..63 -> WtB[(h*64+j)][128]; 1024 slots of 16B, 16/row.
    // LDS image: slot(nrow,kc) = nrow*16 + (kc ^ (nrow&7)); linear dest.
    {
        #pragma unroll
        for (int i = 0; i < 4; ++i) {
            int s = (w << 8) + (i << 6) + l;      // 0..1023
            int nrow = s >> 4;
            int kc = (s & 15) ^ (nrow & 7);
            const char* src = (const char*)WtB + (size_t)(h * 64 + nrow) * 256 + kc * 16;
            __builtin_amdgcn_global_load_lds(
                (const __attribute__((address_space(1))) void*)src,
                (__attribute__((address_space(3))) void*)((char*)Bls + (((w << 8) + (i << 6)) << 4)),
                16, 0, 0);
        }
    }
    __syncthreads();

    f32x4 acc[4] = {};
    #pragma unroll
    for (int ks = 0; ks < 4; ++ks) {
        short8v a = *(const short8v*)&af[ks];
        #pragma unroll
        for (int nt = 0; nt < 4; ++nt) {
            int nrow = (nt << 4) + m16;
            const short8v b = *(const short8v*)((const char*)Bls +
                ((nrow * 256 + (ks << 6) + (g << 4)) ^ ((nrow & 7) << 4)));
            acc[nt] = __builtin_amdgcn_mfma_f32_16x16x32_bf16(a, b, acc[nt], 0, 0, 0);
        }
    }

    const int rbase = mt * 64 + (w << 4) + (g << 2);
    #pragma unroll
    for (int nt = 0; nt < 4; ++nt) {
        int col = h * 64 + (nt << 4) + m16;
        float bv = b_bond[col];
        #pragma unroll
        for (int r = 0; r < 4; ++r) {
            int grow = rbase + r;
            if (grow < N_ATOMS) {
                float* p = out + (size_t)grow * 512 + col;
                *p = *p + acc[nt][r] + bv;
            }
        }
    }
}

// ---------------------------------------------------------------------------
extern "C" void kernel_launch(void* const* d_in, const int* in_sizes, int n_in,
                              void* d_out, int out_size, void* d_ws, size_t ws_size,
                              hipStream_t stream) {
    const float* x        = (const float*)d_in[0];
    const float* edge     = (const float*)d_in[1];
    const float* W_atom   = (const float*)d_in[2];
    const float* b_atom   = (const float*)d_in[3];
    const float* W_bond   = (const float*)d_in[4];
    const float* b_bond   = (const float*)d_in[5];
    const float* att_src  = (const float*)d_in[6];
    const float* att_dst  = (const float*)d_in[7];
    const float* att_edge = (const float*)d_in[8];
    const int*   a2a      = (const int*)d_in[9];
    const int*   a2b      = (const int*)d_in[10];
    float* out = (float*)d_out;

    char* ws = (char*)d_ws;
    unsigned short* hA   = (unsigned short*)ws;                    // 20,480,000
    unsigned short* Zb   = (unsigned short*)(ws + 20480000);       // 40,960,000
    unsigned short* WtA  = (unsigned short*)(ws + 61440000);       // 262,144
    unsigned short* WtB  = (unsigned short*)(ws + 61702144);       // 131,072
    float* s_src_all     = (float*)(ws + 61833216);                // 640,000
    float* s_dst_all     = (float*)(ws + 62473216);                // 640,000
    float* score_edge    = (float*)(ws + 63113216);                // 6,400,000
    float* u_edge        = (float*)(ws + 69513216);                // 4,096
    float* c_edge        = (float*)(ws + 69517312);                // 32

    wt_kernel<<<(512 * 256 + 255) / 256, 256, 0, stream>>>(W_atom, WtA, 256);
    wt_kernel<<<(512 * 128 + 255) / 256, 256, 0, stream>>>(W_bond, WtB, 128);
    uedge_kernel<<<4, 256, 0, stream>>>(W_bond, att_edge, b_bond, u_edge, c_edge);

    // hA = x @ W_atom + b_atom  (bf16)
    gemm_kernel<<<313 * 8, 256, 0, stream>>>(x, WtA, b_atom, hA, N_ATOMS, 256, 313);

    sdots_kernel<<<5000, 256, 0, stream>>>(hA, att_src, att_dst, s_src_all, s_dst_all);
    escore_kernel<<<6250, 256, 0, stream>>>(edge, u_edge, c_edge, score_edge);

    attn_kernel<<<5000, 256, 0, stream>>>(
        hA, edge, s_src_all, s_dst_all, score_edge, a2a, a2b, out, Zb);

    proj_kernel<<<313 * 8, 256, 0, stream>>>(Zb, WtB, b_bond, out);
}

// Round 9
// 172.398 us; speedup vs baseline: 1.4251x; 1.2081x over previous
//
#include <hip/hip_runtime.h>
#include <hip/hip_bf16.h>

#define N_ATOMS 20000
#define N_BONDS 200000
#define MAX_DEG 12
#define IN_DIM 256
#define BOND_DIM 128
#define OUT_DIM 512
#define N_HEADS 8
#define HEAD_DIM 64

typedef __attribute__((ext_vector_type(8))) short short8v;
typedef __attribute__((ext_vector_type(4))) float f32x4;

static __device__ __forceinline__ float bf2f(unsigned int u) {
    union { unsigned int i; float f; } c;
    c.i = (u & 0xffffu) << 16;
    return c.f;
}
static __device__ __forceinline__ unsigned short f2bf(float f) {
    union { float f; unsigned int i; } c;
    c.f = f;
    unsigned int x = c.i;
    x += 0x7fffu + ((x >> 16) & 1u);   // round-to-nearest-even
    return (unsigned short)(x >> 16);
}

// ---------------------------------------------------------------------------
// Wt[n][k] = bf16(W[k][n])  (N fixed 512)
// ---------------------------------------------------------------------------
__global__ void wt_kernel(const float* __restrict__ W, unsigned short* __restrict__ Wt,
                          int K) {
    int id = blockIdx.x * 256 + threadIdx.x;
    if (id >= K * 512) return;
    int n = id / K, k = id % K;
    Wt[id] = f2bf(W[(size_t)k * 512 + n]);
}

// ---------------------------------------------------------------------------
// u_edge[h][c] = sum_k W_bond[c][h*64+k] * att_edge[h][k];  c_edge[h] = b_bond.att_edge
// ---------------------------------------------------------------------------
__global__ void uedge_kernel(const float* __restrict__ Wb, const float* __restrict__ att_edge,
                             const float* __restrict__ b_bond,
                             float* __restrict__ u_edge, float* __restrict__ c_edge) {
    int tid = blockIdx.x * 256 + threadIdx.x;
    if (tid >= 1024) return;
    int h = tid >> 7, c = tid & 127;
    const float* wrow = Wb + (size_t)c * 512 + h * 64;
    const float* ae = att_edge + h * 64;
    float s = 0.f;
    #pragma unroll 8
    for (int k = 0; k < 64; ++k) s += wrow[k] * ae[k];
    u_edge[h * 128 + c] = s;
    if (c == 0) {
        float cs = 0.f;
        const float* bb = b_bond + h * 64;
        for (int k = 0; k < 64; ++k) cs += bb[k] * ae[k];
        c_edge[h] = cs;
    }
}

// ---------------------------------------------------------------------------
// Per-atom score tables from hA: s_src_all[n][h], s_dst_all[n][h].
// ---------------------------------------------------------------------------
__global__ __launch_bounds__(256) void sdots_kernel(
    const unsigned short* __restrict__ hA,
    const float* __restrict__ att_src, const float* __restrict__ att_dst,
    float* __restrict__ s_src_all, float* __restrict__ s_dst_all) {
    const int w = threadIdx.x >> 6, l = threadIdx.x & 63;
    const int n = blockIdx.x * 4 + w;
    if (n >= N_ATOMS) return;
    float4 s0 = *(const float4*)(att_src + l * 8);
    float4 s1 = *(const float4*)(att_src + l * 8 + 4);
    float4 d0 = *(const float4*)(att_dst + l * 8);
    float4 d1 = *(const float4*)(att_dst + l * 8 + 4);
    uint4 u = *(const uint4*)(hA + (size_t)n * 512 + l * 8);
    float fa[8];
    fa[0]=bf2f(u.x); fa[1]=bf2f(u.x>>16); fa[2]=bf2f(u.y); fa[3]=bf2f(u.y>>16);
    fa[4]=bf2f(u.z); fa[5]=bf2f(u.z>>16); fa[6]=bf2f(u.w); fa[7]=bf2f(u.w>>16);
    float ps = fa[0]*s0.x + fa[1]*s0.y + fa[2]*s0.z + fa[3]*s0.w
             + fa[4]*s1.x + fa[5]*s1.y + fa[6]*s1.z + fa[7]*s1.w;
    float pd = fa[0]*d0.x + fa[1]*d0.y + fa[2]*d0.z + fa[3]*d0.w
             + fa[4]*d1.x + fa[5]*d1.y + fa[6]*d1.z + fa[7]*d1.w;
    ps += __shfl_xor(ps, 1); ps += __shfl_xor(ps, 2); ps += __shfl_xor(ps, 4);
    pd += __shfl_xor(pd, 1); pd += __shfl_xor(pd, 2); pd += __shfl_xor(pd, 4);
    if ((l & 7) == 0) {
        s_src_all[n * 8 + (l >> 3)] = ps;
        s_dst_all[n * 8 + (l >> 3)] = pd;
    }
}

// ---------------------------------------------------------------------------
// score_edge[b][h] = edge[b] . u_edge[h] + c_edge[h].  32 bonds/block.
// ---------------------------------------------------------------------------
__global__ __launch_bounds__(256) void escore_kernel(
    const float* __restrict__ edge, const float* __restrict__ u_edge,
    const float* __restrict__ c_edge, float* __restrict__ score_edge) {
    __shared__ float eL[32 * 132];       // padded rows (bank-spread)
    __shared__ float uL[8 * 132];
    __shared__ float cL[8];
    const int t = threadIdx.x;
    const size_t b0 = (size_t)blockIdx.x * 32;
    #pragma unroll
    for (int i = 0; i < 4; ++i) {
        int idx = i * 256 + t;           // f32x4 chunk 0..1023
        int row = idx >> 5, c4 = idx & 31;
        *(float4*)(eL + row * 132 + c4 * 4) = *(const float4*)(edge + b0 * 128 + idx * 4);
    }
    {
        int h = t >> 5, c4 = t & 31;
        *(float4*)(uL + h * 132 + c4 * 4) = *(const float4*)(u_edge + h * 128 + c4 * 4);
    }
    if (t < 8) cL[t] = c_edge[t];
    __syncthreads();
    const int b2 = t >> 3, h = t & 7;
    float s = 0.f;
    #pragma unroll
    for (int c4 = 0; c4 < 32; ++c4) {
        float4 e = *(const float4*)(eL + b2 * 132 + c4 * 4);
        float4 u = *(const float4*)(uL + h * 132 + c4 * 4);
        s += e.x*u.x + e.y*u.y + e.z*u.z + e.w*u.w;
    }
    score_edge[(b0 + b2) * 8 + h] = s + cL[h];
}

// ---------------------------------------------------------------------------
// ATOM GEMM (round-4, proven): tiles 64x64x64, 4 waves, XCD-chunked swizzle.
// ---------------------------------------------------------------------------
__global__ __launch_bounds__(256) void gemm_kernel(
    const float* __restrict__ A, const unsigned short* __restrict__ Wt,
    const float* __restrict__ bias, unsigned short* __restrict__ H,
    int M, int K, int nbm) {
    __shared__ unsigned short Als[64 * 64];
    __shared__ unsigned short Bls[64 * 64];
    const int t = threadIdx.x;
    const int wgid = (blockIdx.x & 7) * nbm + (blockIdx.x >> 3);
    const int bn = wgid & 7;
    const int bm = wgid >> 3;
    const int w = t >> 6;
    const int l = t & 63;

    f32x4 acc[4] = {};

    const int nk = K >> 6;
    for (int kk = 0; kk < nk; ++kk) {
        #pragma unroll
        for (int i = 0; i < 2; ++i) {
            int c = t + i * 256;
            int row = c >> 3;
            int k8 = (c & 7) << 3;
            int grow = (bm << 6) + row;
            float f[8];
            if (grow < M) {
                const float* src = A + (size_t)grow * K + (kk << 6) + k8;
                float4 v0 = *(const float4*)src;
                float4 v1 = *(const float4*)(src + 4);
                f[0] = v0.x; f[1] = v0.y; f[2] = v0.z; f[3] = v0.w;
                f[4] = v1.x; f[5] = v1.y; f[6] = v1.z; f[7] = v1.w;
            } else {
                #pragma unroll
                for (int j = 0; j < 8; ++j) f[j] = 0.f;
            }
            union { unsigned short us[8]; uint4 v; } pk;
            #pragma unroll
            for (int j = 0; j < 8; ++j) pk.us[j] = f2bf(f[j]);
            int byte = ((row << 7) + (k8 << 1)) ^ ((row & 7) << 4);
            *(uint4*)((char*)Als + byte) = pk.v;
        }
        #pragma unroll
        for (int i = 0; i < 2; ++i) {
            int c = t + i * 256;
            int row = c >> 3;
            int k8 = (c & 7) << 3;
            int gn = (bn << 6) + row;
            uint4 v = *(const uint4*)(Wt + (size_t)gn * K + (kk << 6) + k8);
            int byte = ((row << 7) + (k8 << 1)) ^ ((row & 7) << 4);
            *(uint4*)((char*)Bls + byte) = v;
        }
        __syncthreads();

        const int m = l & 15;
        const int kg = (l >> 4) << 3;
        #pragma unroll
        for (int ks = 0; ks < 2; ++ks) {
            int kcol = (ks << 5) + kg;
            int arow = (w << 4) + m;
            short8v a = *(short8v*)((char*)Als +
                (((arow << 7) + (kcol << 1)) ^ ((arow & 7) << 4)));
            #pragma unroll
            for (int nt = 0; nt < 4; ++nt) {
                int nrow = (nt << 4) + m;
                short8v b = *(short8v*)((char*)Bls +
                    (((nrow << 7) + (kcol << 1)) ^ ((nrow & 7) << 4)));
                acc[nt] = __builtin_amdgcn_mfma_f32_16x16x32_bf16(a, b, acc[nt], 0, 0, 0);
            }
        }
        __syncthreads();
    }

    const int m = l & 15;
    const int rbase = (bm << 6) + (w << 4) + ((l >> 4) << 2);
    #pragma unroll
    for (int nt = 0; nt < 4; ++nt) {
        int col = (bn << 6) + (nt << 4) + m;
        float bv = bias[col];
        #pragma unroll
        for (int r = 0; r < 4; ++r) {
            int grow = rbase + r;
            if (grow < M) H[(size_t)grow * 512 + col] = f2bf(acc[nt][r] + bv);
        }
    }
}

// ---------------------------------------------------------------------------
// Fused attention v2: per-lane softmax for OWN head only (h = l>>3).
// Lane l: atom-value part for channels l*8..+8 (head h), and z-part for
// edge channels (l&7)*16..+16 of head h (8 lanes per head cover all 128).
// No shuffles, no redundant 8-head math. Z[n][h][128] bf16 out.
// ---------------------------------------------------------------------------
__global__ __launch_bounds__(256) void attn_kernel(
    const unsigned short* __restrict__ hA,
    const float* __restrict__ edge,
    const float* __restrict__ s_src_all,
    const float* __restrict__ s_dst_all,
    const float* __restrict__ score_edge,
    const int* __restrict__ a2a,
    const int* __restrict__ a2b,
    float* __restrict__ out,
    unsigned short* __restrict__ Z) {
    const int w = threadIdx.x >> 6;
    const int l = threadIdx.x & 63;
    const int n = blockIdx.x * 4 + w;
    if (n >= N_ATOMS) return;
    const int h = l >> 3, sub = l & 7;

    const float ss = s_src_all[n * 8 + h];

    float mrun = -1e30f, lsum = 0.f;
    float acc[8];
    float z[16];
    #pragma unroll
    for (int j = 0; j < 8; ++j) acc[j] = 0.f;
    #pragma unroll
    for (int j = 0; j < 16; ++j) z[j] = 0.f;

    const int* pa = a2a + n * MAX_DEG;
    const int* pb = a2b + n * MAX_DEG;

    for (int d = 0; d < MAX_DEG; ++d) {
        const int ia = pa[d];
        const int ib = pb[d];
        const bool valid = (ia != 0);

        const float sd = s_dst_all[ia * 8 + h];
        const float se = score_edge[ib * 8 + h];
        uint4 ua = *(const uint4*)(hA + (size_t)ia * 512 + l * 8);
        const float* ep = edge + (size_t)ib * 128 + sub * 16;
        float4 e0 = *(const float4*)(ep);
        float4 e1 = *(const float4*)(ep + 4);
        float4 e2 = *(const float4*)(ep + 8);
        float4 e3 = *(const float4*)(ep + 12);

        float sc = ss + sd + se;
        sc = sc > 0.f ? sc : 0.2f * sc;              // leaky_relu(0.2)
        float mn = valid ? fmaxf(mrun, sc) : mrun;
        float scale = __expf(mrun - mn);             // ==1 when masked
        float pw = valid ? __expf(sc - mn) : 0.f;
        lsum = lsum * scale + pw;
        mrun = mn;

        float fa[8];
        fa[0]=bf2f(ua.x); fa[1]=bf2f(ua.x>>16); fa[2]=bf2f(ua.y); fa[3]=bf2f(ua.y>>16);
        fa[4]=bf2f(ua.z); fa[5]=bf2f(ua.z>>16); fa[6]=bf2f(ua.w); fa[7]=bf2f(ua.w>>16);

        #pragma unroll
        for (int j = 0; j < 8; ++j) acc[j] = acc[j] * scale + pw * fa[j];
        z[0]  = z[0]  * scale + pw * e0.x;  z[1]  = z[1]  * scale + pw * e0.y;
        z[2]  = z[2]  * scale + pw * e0.z;  z[3]  = z[3]  * scale + pw * e0.w;
        z[4]  = z[4]  * scale + pw * e1.x;  z[5]  = z[5]  * scale + pw * e1.y;
        z[6]  = z[6]  * scale + pw * e1.z;  z[7]  = z[7]  * scale + pw * e1.w;
        z[8]  = z[8]  * scale + pw * e2.x;  z[9]  = z[9]  * scale + pw * e2.y;
        z[10] = z[10] * scale + pw * e2.z;  z[11] = z[11] * scale + pw * e2.w;
        z[12] = z[12] * scale + pw * e3.x;  z[13] = z[13] * scale + pw * e3.y;
        z[14] = z[14] * scale + pw * e3.z;  z[15] = z[15] * scale + pw * e3.w;
    }

    const float inv = lsum > 0.f ? 1.f / lsum : 0.f;

    float4 o0, o1;
    o0.x = acc[0]*inv; o0.y = acc[1]*inv; o0.z = acc[2]*inv; o0.w = acc[3]*inv;
    o1.x = acc[4]*inv; o1.y = acc[5]*inv; o1.z = acc[6]*inv; o1.w = acc[7]*inv;
    float* dst = out + (size_t)n * 512 + l * 8;
    *(float4*)dst = o0;
    *(float4*)(dst + 4) = o1;

    // Z[n][h*128 + sub*16 .. +16] = z*inv (bf16): lane l -> 32B at l*32, coalesced
    union { unsigned int u[8]; uint4 v[2]; } zp;
    #pragma unroll
    for (int i = 0; i < 8; ++i)
        zp.u[i] = (unsigned int)f2bf(z[2*i] * inv)
                | ((unsigned int)f2bf(z[2*i+1] * inv) << 16);
    unsigned short* zdst = Z + (size_t)n * 1024 + l * 16;
    *(uint4*)zdst = zp.v[0];
    *(uint4*)(zdst + 8) = zp.v[1];
}

// ---------------------------------------------------------------------------
// Projection pass: out[n][h*64+j] += (Z[n][h] @ WtB_head) + b_bond.
// Single-shot 64x64 K=128 MFMA tile per block (bond-v2 structure):
// B (head slice of WtB, 16 KB) via global_load_lds, A (Z rows) to registers.
// ---------------------------------------------------------------------------
__global__ __launch_bounds__(256, 4) void proj_kernel(
    const unsigned short* __restrict__ Z, const unsigned short* __restrict__ WtB,
    const float* __restrict__ b_bond, float* __restrict__ out) {
    __shared__ unsigned short Bls[64 * 128];      // 16 KB
    const int t = threadIdx.x;
    const int w = t >> 6, l = t & 63;
    const int h = blockIdx.x & 7;                 // head
    const int mt = blockIdx.x >> 3;               // 0..312

    const int m16 = l & 15, g = l >> 4;
    const int arow = mt * 64 + (w << 4) + m16;    // atom row (may exceed 19999)

    // A: fragment-shaped Z loads (bf16 direct)
    const unsigned short* Zr = Z + (size_t)arow * 1024 + h * 128 + (g << 3);
    uint4 af[4];
    #pragma unroll
    for (int ks = 0; ks < 4; ++ks)
        af[ks] = *(const uint4*)(Zr + (ks << 5));

    // stage B: rows j=0..63 -> WtB[(h*64+j)][128]; 1024 slots of 16B, 16/row.
    // LDS image: slot(nrow,kc) = nrow*16 + (kc ^ (nrow&7)); linear dest.
    {
        #pragma unroll
        for (int i = 0; i < 4; ++i) {
            int s = (w << 8) + (i << 6) + l;      // 0..1023
            int nrow = s >> 4;
            int kc = (s & 15) ^ (nrow & 7);
            const char* src = (const char*)WtB + (size_t)(h * 64 + nrow) * 256 + kc * 16;
            __builtin_amdgcn_global_load_lds(
                (const __attribute__((address_space(1))) void*)src,
                (__attribute__((address_space(3))) void*)((char*)Bls + (((w << 8) + (i << 6)) << 4)),
                16, 0, 0);
        }
    }
    __syncthreads();

    f32x4 acc[4] = {};
    #pragma unroll
    for (int ks = 0; ks < 4; ++ks) {
        short8v a = *(const short8v*)&af[ks];
        #pragma unroll
        for (int nt = 0; nt < 4; ++nt) {
            int nrow = (nt << 4) + m16;
            const short8v b = *(const short8v*)((const char*)Bls +
                ((nrow * 256 + (ks << 6) + (g << 4)) ^ ((nrow & 7) << 4)));
            acc[nt] = __builtin_amdgcn_mfma_f32_16x16x32_bf16(a, b, acc[nt], 0, 0, 0);
        }
    }

    const int rbase = mt * 64 + (w << 4) + (g << 2);
    #pragma unroll
    for (int nt = 0; nt < 4; ++nt) {
        int col = h * 64 + (nt << 4) + m16;
        float bv = b_bond[col];
        #pragma unroll
        for (int r = 0; r < 4; ++r) {
            int grow = rbase + r;
            if (grow < N_ATOMS) {
                float* p = out + (size_t)grow * 512 + col;
                *p = *p + acc[nt][r] + bv;
            }
        }
    }
}

// ---------------------------------------------------------------------------
extern "C" void kernel_launch(void* const* d_in, const int* in_sizes, int n_in,
                              void* d_out, int out_size, void* d_ws, size_t ws_size,
                              hipStream_t stream) {
    const float* x        = (const float*)d_in[0];
    const float* edge     = (const float*)d_in[1];
    const float* W_atom   = (const float*)d_in[2];
    const float* b_atom   = (const float*)d_in[3];
    const float* W_bond   = (const float*)d_in[4];
    const float* b_bond   = (const float*)d_in[5];
    const float* att_src  = (const float*)d_in[6];
    const float* att_dst  = (const float*)d_in[7];
    const float* att_edge = (const float*)d_in[8];
    const int*   a2a      = (const int*)d_in[9];
    const int*   a2b      = (const int*)d_in[10];
    float* out = (float*)d_out;

    char* ws = (char*)d_ws;
    unsigned short* hA   = (unsigned short*)ws;                    // 20,480,000
    unsigned short* Zb   = (unsigned short*)(ws + 20480000);       // 40,960,000
    unsigned short* WtA  = (unsigned short*)(ws + 61440000);       // 262,144
    unsigned short* WtB  = (unsigned short*)(ws + 61702144);       // 131,072
    float* s_src_all     = (float*)(ws + 61833216);                // 640,000
    float* s_dst_all     = (float*)(ws + 62473216);                // 640,000
    float* score_edge    = (float*)(ws + 63113216);                // 6,400,000
    float* u_edge        = (float*)(ws + 69513216);                // 4,096
    float* c_edge        = (float*)(ws + 69517312);                // 32

    wt_kernel<<<(512 * 256 + 255) / 256, 256, 0, stream>>>(W_atom, WtA, 256);
    wt_kernel<<<(512 * 128 + 255) / 256, 256, 0, stream>>>(W_bond, WtB, 128);
    uedge_kernel<<<4, 256, 0, stream>>>(W_bond, att_edge, b_bond, u_edge, c_edge);

    // hA = x @ W_atom + b_atom  (bf16)
    gemm_kernel<<<313 * 8, 256, 0, stream>>>(x, WtA, b_atom, hA, N_ATOMS, 256, 313);

    sdots_kernel<<<5000, 256, 0, stream>>>(hA, att_src, att_dst, s_src_all, s_dst_all);
    escore_kernel<<<6250, 256, 0, stream>>>(edge, u_edge, c_edge, score_edge);

    attn_kernel<<<5000, 256, 0, stream>>>(
        hA, edge, s_src_all, s_dst_all, score_edge, a2a, a2b, out, Zb);

    proj_kernel<<<313 * 8, 256, 0, stream>>>(Zb, WtB, b_bond, out);
}